// Round 1
// 187.422 us; speedup vs baseline: 1.0667x; 1.0667x over previous
//
#include <hip/hip_runtime.h>
#include <math.h>

// Problem constants (B=4, S=4096, D=2048, fp32)
#define NBATCH 4
#define SROWS  4096
#define DCOLS  2048
#define BPB    128                              // blocks per batch
#define NBLK1  (NBATCH * BPB)                   // 512
#define ROWS_PER_WAVE (SROWS / (BPB * 4))       // = 8

// Workspace layout:
//   part    : float [NBLK1][DCOLS]   = 4 MiB   (per-block partial column sums)
//   ssq_part: double[64]             (per-block partial sum-of-squares)
//   counter : unsigned               (last-block handshake, re-init by kernel 1)
#define SSQ_OFFSET ((size_t)NBLK1 * DCOLS)      // in floats

typedef float v4f __attribute__((ext_vector_type(4)));

// Kernel 1: per-block partial of s_b[d] = sum_i h[b,i,d] / max(||h[b,i,:]||, eps).
// Wave-per-row: 64 lanes x 8 float4 segments = 2048 columns. fp32 partials over
// 8 rows/wave, LDS reduce across the block's 4 waves, coalesced partial store.
// h is streamed once -> non-temporal loads (keeps `part` L3-resident for k2).
// Also re-initializes the handshake counter each launch (graph-replay safe:
// stream order guarantees all of kernel 1 completes before kernel 2 starts).
__global__ __launch_bounds__(256, 2)
void row_normalize_sum(const float* __restrict__ h, float* __restrict__ part,
                       unsigned* __restrict__ counter) {
    if (blockIdx.x == 0 && threadIdx.x == 0) *counter = 0u;

    const int b    = blockIdx.x >> 7;            // / BPB (BPB == 128)
    const int blk  = blockIdx.x & (BPB - 1);
    const int wave = threadIdx.x >> 6;           // 0..3
    const int lane = threadIdx.x & 63;

    const float* hb = h + (size_t)b * SROWS * DCOLS;
    const int wid      = blk * 4 + wave;         // 0..511 within batch
    const int row_base = wid * ROWS_PER_WAVE;

    float acc[32];
#pragma unroll
    for (int i = 0; i < 32; ++i) acc[i] = 0.0f;

    for (int r = 0; r < ROWS_PER_WAVE; r += 2) {
        const v4f* p0 = (const v4f*)(hb + (size_t)(row_base + r)     * DCOLS) + lane;
        const v4f* p1 = (const v4f*)(hb + (size_t)(row_base + r + 1) * DCOLS) + lane;
        v4f v0[8], v1[8];
#pragma unroll
        for (int s = 0; s < 8; ++s) v0[s] = __builtin_nontemporal_load(p0 + s * 64);
#pragma unroll
        for (int s = 0; s < 8; ++s) v1[s] = __builtin_nontemporal_load(p1 + s * 64);

        float ss0 = 0.0f, ss1 = 0.0f;
#pragma unroll
        for (int s = 0; s < 8; ++s) {
#pragma unroll
            for (int j = 0; j < 4; ++j) {
                ss0 += v0[s][j] * v0[s][j];
                ss1 += v1[s][j] * v1[s][j];
            }
        }
        // 64-lane butterfly reduction (wave = 64 on CDNA)
#pragma unroll
        for (int m = 32; m >= 1; m >>= 1) {
            ss0 += __shfl_xor(ss0, m, 64);
            ss1 += __shfl_xor(ss1, m, 64);
        }
        // inv = 1 / max(||row||, eps); double sqrt once per row for accuracy
        const float inv0 = (float)(1.0 / fmax(sqrt((double)ss0), 1e-12));
        const float inv1 = (float)(1.0 / fmax(sqrt((double)ss1), 1e-12));
#pragma unroll
        for (int s = 0; s < 8; ++s) {
#pragma unroll
            for (int j = 0; j < 4; ++j) {
                acc[s * 4 + j] += v0[s][j] * inv0;
                acc[s * 4 + j] += v1[s][j] * inv1;
            }
        }
    }

    // Block reduction across the 4 waves via LDS (32 KiB), then coalesced store.
    __shared__ float red[4][DCOLS];
#pragma unroll
    for (int s = 0; s < 8; ++s) {
        v4f v;
#pragma unroll
        for (int j = 0; j < 4; ++j) v[j] = acc[s * 4 + j];
        *(v4f*)&red[wave][s * 256 + lane * 4] = v;
    }
    __syncthreads();

    float* dst = part + (size_t)blockIdx.x * DCOLS;
#pragma unroll
    for (int k = 0; k < 8; ++k) {
        const int c = k * 256 + threadIdx.x;
        dst[c] = red[0][c] + red[1][c] + red[2][c] + red[3][c];
    }
}

// Kernel 2 (fused with old kernel 3): 64 blocks. Block k: batch b = k>>4,
// columns [(k&15)*128, +128). Sum the batch's 128 partials per column in
// double, square, block-reduce, publish one ssq partial per block, and let
// the LAST block (device-scope counter) do the 64-wide final reduce +
// sigmoid and write the outputs.
__global__ __launch_bounds__(256, 4)
void reduce_partials_finalize(const float* __restrict__ part,
                              double* __restrict__ ssq_part,
                              unsigned* __restrict__ counter,
                              const float* __restrict__ alpha,
                              const float* __restrict__ beta,
                              float* __restrict__ out) {
    const int b    = blockIdx.x >> 4;
    const int c    = ((blockIdx.x & 15) * 128) + (threadIdx.x & 127);
    const int half = threadIdx.x >> 7;           // 0 or 1
    const float* pb = part + (size_t)b * BPB * DCOLS;

    double sum = 0.0;
    const int pstart = half * 64;
#pragma unroll 16
    for (int p = pstart; p < pstart + 64; ++p)
        sum += (double)pb[(size_t)p * DCOLS + c];

    __shared__ double sh[256];
    sh[threadIdx.x] = sum;
    __syncthreads();

    double ssq = 0.0;
    if (threadIdx.x < 128) {
        const double s2 = sh[threadIdx.x] + sh[threadIdx.x + 128];
        ssq = s2 * s2;
    }
    __syncthreads();
    sh[threadIdx.x] = ssq;
    __syncthreads();
    for (int off = 64; off > 0; off >>= 1) {
        if (threadIdx.x < off) sh[threadIdx.x] += sh[threadIdx.x + off];
        __syncthreads();
    }

    // Publish this block's partial with agent-scope release, then bump the
    // counter. The block that sees 63 is last: all 64 partials are visible
    // (release->acquire pairing at agent scope; no cross-XCD staleness).
    __shared__ int lastFlag;
    if (threadIdx.x == 0) {
        __hip_atomic_store(&ssq_part[blockIdx.x], sh[0],
                           __ATOMIC_RELEASE, __HIP_MEMORY_SCOPE_AGENT);
        const unsigned t = __hip_atomic_fetch_add(counter, 1u,
                           __ATOMIC_ACQ_REL, __HIP_MEMORY_SCOPE_AGENT);
        lastFlag = (t == 63u) ? 1 : 0;
    }
    __syncthreads();

    if (lastFlag && threadIdx.x < 64) {
        double v = __hip_atomic_load(&ssq_part[threadIdx.x],
                                     __ATOMIC_ACQUIRE, __HIP_MEMORY_SCOPE_AGENT);
#pragma unroll
        for (int m = 32; m >= 1; m >>= 1) v += __shfl_xor(v, m, 64);
        if (threadIdx.x == 0) {
            const double num   = v - (double)NBATCH * (double)SROWS;
            const double denom = (double)NBATCH * (double)SROWS * (double)(SROWS - 1);
            const double conc  = num / denom;
            const double a  = (double)alpha[0];
            const double bt = (double)beta[0];
            const double lam = 1.0 / (1.0 + exp(-a * (conc - bt)));
            out[0] = (float)lam;   // lambda_t
            out[1] = (float)conc;  // conc
        }
    }
}

extern "C" void kernel_launch(void* const* d_in, const int* in_sizes, int n_in,
                              void* d_out, int out_size, void* d_ws, size_t ws_size,
                              hipStream_t stream) {
    (void)in_sizes; (void)n_in; (void)out_size; (void)ws_size;
    const float* h     = (const float*)d_in[0];
    const float* alpha = (const float*)d_in[1];
    const float* beta  = (const float*)d_in[2];
    float* out         = (float*)d_out;
    float* part        = (float*)d_ws;                         // 4 MiB partials
    double* ssq_part   = (double*)((float*)d_ws + SSQ_OFFSET); // 64 doubles
    unsigned* counter  = (unsigned*)(ssq_part + 64);           // handshake

    row_normalize_sum<<<NBLK1, 256, 0, stream>>>(h, part, counter);
    reduce_partials_finalize<<<64, 256, 0, stream>>>(part, ssq_part, counter,
                                                     alpha, beta, out);
}